// Round 5
// baseline (604.479 us; speedup 1.0000x reference)
//
#include <hip/hip_runtime.h>
#include <hip/hip_cooperative_groups.h>

namespace cg = cooperative_groups;

// Problem constants
#define D    128      // d+1
#define DM   127      // d
#define NP1  1024     // N+1
#define B    8
#define H    8
#define NL   4

// Workspace layout (float offsets) — 1,310,720 floats = 5 MB total (< proven 6 MB)
#define WS_QF 0                        // [H][128][128] padded Q (current layer; params[:,1])
#define WS_PT (WS_QF + H*D*D)          // [H][128][128] padded+transposed P (params[:,0])
#define WS_GP (WS_PT + H*D*D)          // [B][8][128][128] Gram partials (8 token-chunks)
#define WS_SP (WS_GP + B*8*D*D)        // [B][H][128][128] per-head S partials

// ---------------------------------------------------------------------------
// Param prep for ONE layer: pad Q -> Qf, pad+transpose P -> Pt.
// 256 blocks x 256 threads; 2*H*128*128 = 262144 elements, 4 per thread.
// Reference: params[:,0] = P, params[:,1] = Q.
// ---------------------------------------------------------------------------
__device__ __forceinline__ void prep_body(const float* __restrict__ apl,
                                          float* __restrict__ Qf, float* __restrict__ Pt,
                                          int gid, int t)
{
    const int base = gid * 256 + t;
    #pragma unroll
    for (int e = 0; e < 4; ++e) {
        const int idx   = base + e * 65536;   // 0..262143
        const int isP   = idx >> 17;
        const int local = idx & 131071;
        const int h = local >> 14;
        const int r = (local >> 7) & 127;
        const int c = local & 127;
        if (!isP) {
            float v = (r < DM && c < DM) ? apl[(h * 2 + 1) * DM * DM + r * DM + c] : 0.f;
            Qf[local] = v;
        } else {
            float v;
            if (r < DM && c < DM)        v = apl[(h * 2 + 0) * DM * DM + c * DM + r];
            else if (r == DM && c == DM) v = 1.f;
            else                         v = 0.f;
            Pt[local] = v;
        }
    }
}

// ---------------------------------------------------------------------------
// Gram partials. 256 blocks as (c:8, q:4, b:8).
// Gp[b][c][0:128][32q:32q+32] = sum_{tokens in chunk c, masked} z z^T
// Stages 64 tokens at a time (32 KB LDS), two passes.
// ---------------------------------------------------------------------------
__device__ __forceinline__ void gp_body(const float* __restrict__ Z,
                                        float* __restrict__ Gp,
                                        int gid, int t, float* lds)
{
    const int c = gid & 7;
    const int q = (gid >> 3) & 3;
    const int b = gid >> 5;

    const int ty = t >> 3;            // 0..31 -> rows i0 = 4*ty
    const int tx = t & 7;             // 0..7  -> cols j0 = 32q + 4*tx
    const int i0 = ty * 4;
    const int j0 = q * 32 + tx * 4;

    float acc[4][4] = {};
    #pragma unroll
    for (int half = 0; half < 2; ++half) {
        __syncthreads();   // protect lds reuse (prev half / prev phase)
        const float4* src = (const float4*)(Z + ((size_t)b * NP1 + c * 128 + half * 64) * D);
        #pragma unroll
        for (int i = 0; i < 8; ++i) {
            float4 v = src[t + 256 * i];
            // token 1023 = last row of (chunk 7, half 1) -> masked (key mask)
            if (c == 7 && half == 1 && i == 7 && t >= 224) v = make_float4(0.f, 0.f, 0.f, 0.f);
            ((float4*)lds)[t + 256 * i] = v;
        }
        __syncthreads();
        #pragma unroll 4
        for (int k = 0; k < 64; ++k) {
            const float4 a  = *(const float4*)&lds[k * 128 + i0];
            const float4 cc = *(const float4*)&lds[k * 128 + j0];
            acc[0][0] += a.x * cc.x; acc[0][1] += a.x * cc.y; acc[0][2] += a.x * cc.z; acc[0][3] += a.x * cc.w;
            acc[1][0] += a.y * cc.x; acc[1][1] += a.y * cc.y; acc[1][2] += a.y * cc.z; acc[1][3] += a.y * cc.w;
            acc[2][0] += a.z * cc.x; acc[2][1] += a.z * cc.y; acc[2][2] += a.z * cc.z; acc[2][3] += a.z * cc.w;
            acc[3][0] += a.w * cc.x; acc[3][1] += a.w * cc.y; acc[3][2] += a.w * cc.z; acc[3][3] += a.w * cc.w;
        }
    }

    float* Gb = Gp + ((size_t)(b * 8 + c)) * D * D;
    #pragma unroll
    for (int r = 0; r < 4; ++r)
        *(float4*)&Gb[(i0 + r) * D + j0] = make_float4(acc[r][0], acc[r][1], acc[r][2], acc[r][3]);
}

// ---------------------------------------------------------------------------
// TS phase: T = Qf@G (G-reduce fused into staging), Sp[b][h] = T@Pt.
// 256 blocks as (s:4, h:8, b:8); block computes rows [32s,32s+32). LDS 40 KB.
// ---------------------------------------------------------------------------
__device__ __forceinline__ void ts_body(const float* __restrict__ Qf,
                                        const float* __restrict__ Pt,
                                        const float* __restrict__ Gp,
                                        float* __restrict__ Sp,
                                        int gid, int t, float* lds)
{
    const int s = gid & 3;
    const int h = (gid >> 2) & 7;
    const int b = gid >> 5;

    float* Qs = lds;            // 4096 floats
    float* Cc = lds + 4096;     // 2048 floats
    float* Ts = lds + 6144;     // 4096 floats

    const int ty = t >> 4;      // 0..15 -> rows ty, ty+16
    const int tx = t & 15;
    const int j0 = 4 * tx;
    const int j1 = 64 + 4 * tx;

    const float4* qsrc = (const float4*)(Qf + ((size_t)h * D + s * 32) * D);
    #pragma unroll
    for (int i = 0; i < 4; ++i) ((float4*)Qs)[t + 256 * i] = qsrc[t + 256 * i];

    // ---- phase 1: T rows = Qs @ G[b], G = sum_c Gp[b][c] fused in staging ----
    float acc[2][8] = {};
    const float4* Gp4 = (const float4*)Gp;
    for (int kc = 0; kc < 8; ++kc) {
        __syncthreads();   // also covers Qs visibility on kc==0
        float4 s0 = make_float4(0.f, 0.f, 0.f, 0.f), s1 = s0;
        #pragma unroll
        for (int c = 0; c < 8; ++c) {
            const float4* base = Gp4 + (size_t)(b * 8 + c) * 4096 + kc * 512;
            const float4 v0 = base[t];
            const float4 v1 = base[256 + t];
            s0.x += v0.x; s0.y += v0.y; s0.z += v0.z; s0.w += v0.w;
            s1.x += v1.x; s1.y += v1.y; s1.z += v1.z; s1.w += v1.w;
        }
        ((float4*)Cc)[t]       = s0;
        ((float4*)Cc)[256 + t] = s1;
        __syncthreads();
        #pragma unroll
        for (int kk = 0; kk < 16; ++kk) {
            const float q0 = Qs[ty * 128 + kc * 16 + kk];
            const float q1 = Qs[(ty + 16) * 128 + kc * 16 + kk];
            const float4 g0 = *(const float4*)&Cc[kk * 128 + j0];
            const float4 g1 = *(const float4*)&Cc[kk * 128 + j1];
            acc[0][0] += q0 * g0.x; acc[0][1] += q0 * g0.y; acc[0][2] += q0 * g0.z; acc[0][3] += q0 * g0.w;
            acc[0][4] += q0 * g1.x; acc[0][5] += q0 * g1.y; acc[0][6] += q0 * g1.z; acc[0][7] += q0 * g1.w;
            acc[1][0] += q1 * g0.x; acc[1][1] += q1 * g0.y; acc[1][2] += q1 * g0.z; acc[1][3] += q1 * g0.w;
            acc[1][4] += q1 * g1.x; acc[1][5] += q1 * g1.y; acc[1][6] += q1 * g1.z; acc[1][7] += q1 * g1.w;
        }
    }
    *(float4*)&Ts[ty * 128 + j0]        = make_float4(acc[0][0], acc[0][1], acc[0][2], acc[0][3]);
    *(float4*)&Ts[ty * 128 + j1]        = make_float4(acc[0][4], acc[0][5], acc[0][6], acc[0][7]);
    *(float4*)&Ts[(ty + 16) * 128 + j0] = make_float4(acc[1][0], acc[1][1], acc[1][2], acc[1][3]);
    *(float4*)&Ts[(ty + 16) * 128 + j1] = make_float4(acc[1][4], acc[1][5], acc[1][6], acc[1][7]);

    // ---- phase 2: Sp rows = Ts @ Pt[h] ----
    float bcc[2][8] = {};
    for (int kc = 0; kc < 8; ++kc) {
        __syncthreads();   // covers Ts visibility on kc==0
        const float4* psrc = (const float4*)(Pt + ((size_t)h * D + kc * 16) * D);
        ((float4*)Cc)[t]       = psrc[t];
        ((float4*)Cc)[256 + t] = psrc[256 + t];
        __syncthreads();
        #pragma unroll
        for (int kk = 0; kk < 16; ++kk) {
            const float t0 = Ts[ty * 128 + kc * 16 + kk];
            const float t1 = Ts[(ty + 16) * 128 + kc * 16 + kk];
            const float4 p0 = *(const float4*)&Cc[kk * 128 + j0];
            const float4 p1 = *(const float4*)&Cc[kk * 128 + j1];
            bcc[0][0] += t0 * p0.x; bcc[0][1] += t0 * p0.y; bcc[0][2] += t0 * p0.z; bcc[0][3] += t0 * p0.w;
            bcc[0][4] += t0 * p1.x; bcc[0][5] += t0 * p1.y; bcc[0][6] += t0 * p1.z; bcc[0][7] += t0 * p1.w;
            bcc[1][0] += t1 * p0.x; bcc[1][1] += t1 * p0.y; bcc[1][2] += t1 * p0.z; bcc[1][3] += t1 * p0.w;
            bcc[1][4] += t1 * p1.x; bcc[1][5] += t1 * p1.y; bcc[1][6] += t1 * p1.z; bcc[1][7] += t1 * p1.w;
        }
    }
    float* Sb = Sp + ((size_t)(b * 8 + h)) * D * D;
    const int r0 = s * 32 + ty;
    const int r1 = r0 + 16;
    *(float4*)&Sb[r0 * D + j0] = make_float4(bcc[0][0], bcc[0][1], bcc[0][2], bcc[0][3]);
    *(float4*)&Sb[r0 * D + j1] = make_float4(bcc[0][4], bcc[0][5], bcc[0][6], bcc[0][7]);
    *(float4*)&Sb[r1 * D + j0] = make_float4(bcc[1][0], bcc[1][1], bcc[1][2], bcc[1][3]);
    *(float4*)&Sb[r1 * D + j1] = make_float4(bcc[1][4], bcc[1][5], bcc[1][6], bcc[1][7]);
}

// ---------------------------------------------------------------------------
// Z phase: Zout = Zin + Zin @ S, S = (1/N) sum_h Sp fused into staging.
// 256 blocks as (s:32, b:8); block handles 32 rows (row-exclusive, in-place safe).
// NOTE: Zin may alias out (layers >= 1) — no __restrict__ here.
// ---------------------------------------------------------------------------
__device__ __forceinline__ void z_body(const float* Zin,
                                       const float* __restrict__ Sp,
                                       float* out,
                                       int gid, int t, float* lds)
{
    const int s = gid & 31;
    const int b = gid >> 5;

    float* Zs = lds;            // 32*132 = 4224 floats
    float* Sc = lds + 4224;     // 4096 floats

    const int ty = t >> 3;      // 0..31 -> row
    const int tx = t & 7;       // cols 4tx + 32jj

    const float* Zrow0 = Zin + ((size_t)b * NP1 + s * 32) * D;
    __syncthreads();            // protect lds reuse from previous phase
    for (int q = t; q < 32 * 32; q += 256) {
        const int r = q >> 5, c4 = q & 31;
        *(float4*)&Zs[r * 132 + c4 * 4] = ((const float4*)(Zrow0 + r * D))[c4];
    }

    float acc[16];
    #pragma unroll
    for (int q = 0; q < 16; ++q) acc[q] = 0.f;

    const float4* Sp4 = (const float4*)Sp;
    const float inv = 1.0f / 1023.0f;
    for (int kc = 0; kc < 4; ++kc) {
        __syncthreads();
        #pragma unroll
        for (int p = 0; p < 4; ++p) {
            float4 sum = make_float4(0.f, 0.f, 0.f, 0.f);
            #pragma unroll
            for (int h = 0; h < 8; ++h) {
                const float4 v = Sp4[(size_t)(b * 8 + h) * 4096 + kc * 1024 + p * 256 + t];
                sum.x += v.x; sum.y += v.y; sum.z += v.z; sum.w += v.w;
            }
            ((float4*)Sc)[p * 256 + t] =
                make_float4(sum.x * inv, sum.y * inv, sum.z * inv, sum.w * inv);
        }
        __syncthreads();
        #pragma unroll
        for (int kk = 0; kk < 32; ++kk) {
            const float zv = Zs[ty * 132 + kc * 32 + kk];
            #pragma unroll
            for (int jj = 0; jj < 4; ++jj) {
                const float4 sv = *(const float4*)&Sc[kk * 128 + 4 * tx + 32 * jj];
                acc[jj * 4 + 0] += zv * sv.x;
                acc[jj * 4 + 1] += zv * sv.y;
                acc[jj * 4 + 2] += zv * sv.z;
                acc[jj * 4 + 3] += zv * sv.w;
            }
        }
    }

    float* Orow = out + ((size_t)b * NP1 + s * 32 + ty) * D;
    #pragma unroll
    for (int jj = 0; jj < 4; ++jj) {
        const int col = 4 * tx + 32 * jj;
        const float4 zr = *(const float4*)&Zs[ty * 132 + col];
        *(float4*)(Orow + col) = make_float4(zr.x + acc[jj * 4 + 0], zr.y + acc[jj * 4 + 1],
                                             zr.z + acc[jj * 4 + 2], zr.w + acc[jj * 4 + 3]);
    }
}

// ---------------------------------------------------------------------------
// Primary path: single cooperative kernel, 256 blocks x 256 threads, 40 KB LDS.
// ---------------------------------------------------------------------------
__global__ __launch_bounds__(256) void fused_all(
    const float* Z0, const float* ap, float* out,
    float* Qf, float* Pt, float* Gp, float* Sp)
{
    cg::grid_group grid = cg::this_grid();
    const int gid = blockIdx.x;
    const int t = threadIdx.x;
    __shared__ float lds[10240];   // 40 KB union of all phases

    prep_body(ap, Qf, Pt, gid, t);        // layer 0 params
    gp_body(Z0, Gp, gid, t, lds);         // layer 0 Gram partials
    grid.sync();

    const float* Zcur = Z0;
    for (int l = 0; l < NL; ++l) {
        ts_body(Qf, Pt, Gp, Sp, gid, t, lds);
        grid.sync();
        z_body(Zcur, Sp, out, gid, t, lds);
        if (l < NL - 1) {
            grid.sync();
            prep_body(ap + (size_t)(l + 1) * (H * 2 * DM * DM), Qf, Pt, gid, t);
            gp_body(out, Gp, gid, t, lds);
            grid.sync();
        }
        Zcur = out;
    }
}

// ---------------------------------------------------------------------------
// Fallback path: same bodies as ordinary kernels (12 launches total).
// ---------------------------------------------------------------------------
__global__ __launch_bounds__(256) void gpp_kernel(
    const float* Z, const float* apl, float* Gp, float* Qf, float* Pt)
{
    __shared__ float lds[8192];
    prep_body(apl, Qf, Pt, blockIdx.x, threadIdx.x);
    gp_body(Z, Gp, blockIdx.x, threadIdx.x, lds);
}

__global__ __launch_bounds__(256) void ts_kernel(
    const float* Qf, const float* Pt, const float* Gp, float* Sp)
{
    __shared__ float lds[10240];
    ts_body(Qf, Pt, Gp, Sp, blockIdx.x, threadIdx.x, lds);
}

__global__ __launch_bounds__(256) void z_kernel(
    const float* Zin, const float* Sp, float* out)
{
    __shared__ float lds[8320];
    z_body(Zin, Sp, out, blockIdx.x, threadIdx.x, lds);
}

// ---------------------------------------------------------------------------
extern "C" void kernel_launch(void* const* d_in, const int* in_sizes, int n_in,
                              void* d_out, int out_size, void* d_ws, size_t ws_size,
                              hipStream_t stream)
{
    const float* Z0 = (const float*)d_in[0];
    const float* ap = (const float*)d_in[1];
    float* out = (float*)d_out;
    float* ws  = (float*)d_ws;

    float* Qf = ws + WS_QF;
    float* Pt = ws + WS_PT;
    float* Gp = ws + WS_GP;
    float* Sp = ws + WS_SP;

    void* args[] = { (void*)&Z0, (void*)&ap, (void*)&out,
                     (void*)&Qf, (void*)&Pt, (void*)&Gp, (void*)&Sp };
    hipError_t err = hipLaunchCooperativeKernel((const void*)fused_all, dim3(256),
                                                dim3(256), args, 0, stream);
    if (err != hipSuccess) {
        // Fallback: identical math via ordinary launches (stream-ordered).
        const float* Zcur = Z0;
        for (int l = 0; l < NL; ++l) {
            const float* apl = ap + (size_t)l * H * 2 * DM * DM;
            hipLaunchKernelGGL(gpp_kernel, dim3(256), dim3(256), 0, stream, Zcur, apl, Gp, Qf, Pt);
            hipLaunchKernelGGL(ts_kernel,  dim3(256), dim3(256), 0, stream, Qf, Pt, Gp, Sp);
            hipLaunchKernelGGL(z_kernel,   dim3(256), dim3(256), 0, stream, Zcur, Sp, out);
            Zcur = out;
        }
    }
}